// Round 3
// baseline (5450.444 us; speedup 1.0000x reference)
//
#include <hip/hip_runtime.h>

// WaveguideOutputSimulation: 2D Helmholtz + PML solve.
// A = kron(L,I) + kron(I,L) + k0dx^2 diag(n^2), L = 48x48 complex tridiagonal
// (same for x and y). Block-tridiagonal Thomas with dense 48x48 inverses via
// in-place Gauss-Jordan (no pivoting), in FP64. Single workgroup; active
// matrix in registers (3 complex per thread), one __syncthreads per pivot.
// G history spilled to d_ws as fp32 (backward matvec only).
// Output layout dispatched on out_size: 9216 -> float32 REAL parts (1,48,48,4)
// (harness casts complex64 ref via astype(float32)); 18432 -> interleaved.

#define NXY 48
#define NN  2304      // 48*48
#define NT  768       // threads: 48 rows x 16 segs, 3 complex elems each

typedef double2 zplx;

__device__ __forceinline__ zplx zmul(zplx a, zplx b){
    return make_double2(a.x*b.x - a.y*b.y, a.x*b.y + a.y*b.x);
}
__device__ __forceinline__ zplx zadd(zplx a, zplx b){ return make_double2(a.x+b.x, a.y+b.y); }
__device__ __forceinline__ zplx zsub(zplx a, zplx b){ return make_double2(a.x-b.x, a.y-b.y); }
__device__ __forceinline__ zplx zneg(zplx a){ return make_double2(-a.x, -a.y); }
__device__ __forceinline__ zplx zinv(zplx a){
    double s = 1.0/(a.x*a.x + a.y*a.y);
    return make_double2(a.x*s, -a.y*s);
}

// PML stretch s(u) = (1 + 14 u^3) + i * (0.8*4*40/(2*pi)) * u^3   (pi = 3.1415926)
__device__ __forceinline__ zplx fun_s(double u){
    const double sig = 0.8*4.0*40.0/(2.0*3.1415926);
    double u3 = u*u*u;
    return make_double2(1.0 + 14.0*u3, sig*u3);
}
// s_half[j], j=0..48:  left j<=8: fun_s((8.5-j)/9); right j>=40: fun_s((j-40+0.5)/9)
__device__ __forceinline__ zplx s_half_at(int j){
    if (j <= 8)  return fun_s((8.5 - (double)j)/9.0);
    if (j >= 40) return fun_s(((double)(j-40) + 0.5)/9.0);
    return make_double2(1.0, 0.0);
}
// s_int[j], j=0..47: left j<=7: fun_s((8-j)/9); right j>=40: fun_s((j-40+1)/9)
__device__ __forceinline__ zplx s_int_at(int j){
    if (j <= 7)  return fun_s((8.0 - (double)j)/9.0);
    if (j >= 40) return fun_s(((double)(j-40) + 1.0)/9.0);
    return make_double2(1.0, 0.0);
}

__global__ __launch_bounds__(NT) void helmholtz_solve_kernel(
    const float* __restrict__ n_pred,   // (1,48,48,1) flat, idx = ix*48+iy
    const float* __restrict__ xb,       // (1,48,48,1)
    const float* __restrict__ yaim,     // (1,48,48,2)
    float*       __restrict__ out,
    int                       out_size, // 9216 -> real-only; 18432 -> interleaved
    float2*      __restrict__ wsG)      // 48 * 2304 fp32 complex: stored inverses G_i
{
    __shared__ zplx dg[NXY], lo[NXY], hi[NXY];      // tridiagonal L: diag, sub, super
    __shared__ float nk[NN];                        // k^2 * n(ix,iy)^2 at [iy*48+ix]
    __shared__ zplx zv[NN];                         // z_i / x_i at [i*48+a]
    __shared__ zplx rowbuf[2][NXY], colbuf[2][NXY]; // pivot row/col, parity dbuf
    __shared__ zplx psum[NXY*17];                   // matvec partials, stride 17
    __shared__ zplx tmpv[NXY];
    // total: 2304+9216+36864+3072+13056+768 = 65280 B  (<= 64 KiB)

    const int t  = threadIdx.x;
    const int r  = t / 16;        // row of the 48x48 block this thread serves
    const int s  = t % 16;        // segment: columns 3s..3s+2
    const int c0 = 3*s;
    const double k2 = 0.2026833935483871*0.2026833935483871;

    // ---- setup tridiagonal L (identical for x and y) ----
    if (t < NXY){
        int a = t;
        zplx isha  = zinv(s_half_at(a));
        zplx isha1 = zinv(s_half_at(a+1));
        zplx isi   = zinv(s_int_at(a));
        dg[a] = zneg(zmul(isi, zadd(isha, isha1)));  // L[a,a]
        lo[a] = zmul(isi, isha);                      // L[a,a-1]
        hi[a] = zmul(isi, isha1);                     // L[a,a+1]
    }
    // ---- load n^2 with the [0,2,1,3]-transpose convention ----
    for (int e = t; e < NN; e += NT){
        int a_ = e / 48, i_ = e % 48;   // input element (ix=a_, iy=i_)
        float nv = n_pred[e];
        nk[i_*48 + a_] = (float)(k2 * (double)nv * (double)nv);
    }
    __syncthreads();

    zplx g0 = make_double2(0.0,0.0), g1 = g0, g2 = g0;  // G_{i-1} row r, cols c0..c0+2

    // ================= forward sweep =================
    #pragma unroll 1
    for (int i = 0; i < NXY; ++i){
        // ---- phase A: S_i = T_i - (lo_i*hi_{i-1}) G_{i-1} in registers;
        //      partials of G_{i-1} * z_{i-1} into psum
        zplx m0, m1, m2;
        zplx diag = zadd(zadd(dg[i], dg[r]), make_double2((double)nk[i*48 + r], 0.0));
        zplx ci = (i > 0) ? zmul(lo[i], hi[i-1]) : make_double2(0.0, 0.0);
        {
            zplx g[3] = {g0, g1, g2};
            zplx m[3];
            #pragma unroll
            for (int j = 0; j < 3; ++j){
                int c = c0 + j;
                zplx v = make_double2(0.0, 0.0);
                if (i > 0) v = zneg(zmul(ci, g[j]));
                if      (c == r)   v = zadd(v, diag);
                else if (c == r-1) v = zadd(v, lo[r]);
                else if (c == r+1) v = zadd(v, hi[r]);
                m[j] = v;
            }
            m0 = m[0]; m1 = m[1]; m2 = m[2];
            if (i > 0){
                zplx p = zmul(g0, zv[(i-1)*48 + c0]);
                p = zadd(p, zmul(g1, zv[(i-1)*48 + c0+1]));
                p = zadd(p, zmul(g2, zv[(i-1)*48 + c0+2]));
                psum[r*17 + s] = p;
            }
        }
        // publish pivot row 0 / col 0 (parity 0)
        if (r == 0){ rowbuf[0][c0] = m0; rowbuf[0][c0+1] = m1; rowbuf[0][c0+2] = m2; }
        if (c0 == 0){ colbuf[0][r] = m0; }
        __syncthreads();

        // ---- phase C: z_i = b_i - lo_i * (G_{i-1} z_{i-1}) ----
        // b_i[t] = b[p=i*48+t]; p=iy*48+ix => iy=i, ix=t => xb[t*48+i]
        if (t < NXY){
            double bv = (double)xb[t*48 + i];
            if (i > 0){
                zplx w = psum[t*17];
                #pragma unroll
                for (int q = 1; q < 16; ++q) w = zadd(w, psum[t*17 + q]);
                zv[i*48 + t] = zsub(make_double2(bv, 0.0), zmul(lo[i], w));
            } else {
                zv[t] = make_double2(bv, 0.0);
            }
        }

        // ---- in-place Gauss-Jordan inversion: 48 pivots, 1 barrier each ----
        #pragma unroll 1
        for (int k = 0; k < NXY; ++k){
            int p = k & 1;
            zplx akk  = rowbuf[p][k];
            zplx d    = zinv(akk);
            zplx colr = colbuf[p][r];   // old A[r][k]
            zplx dc   = zmul(d, colr);
            zplx m[3] = {m0, m1, m2};
            zplx n_[3];
            #pragma unroll
            for (int j = 0; j < 3; ++j){
                int c = c0 + j;
                zplx nv;
                if (r == k){
                    nv = (c == k) ? d : zmul(d, m[j]);
                } else if (c == k){
                    nv = zneg(dc);
                } else {
                    zplx rowc = rowbuf[p][c];   // old A[k][c]
                    nv = zsub(m[j], zmul(dc, rowc));
                }
                n_[j] = nv;
            }
            m0 = n_[0]; m1 = n_[1]; m2 = n_[2];
            if (k < NXY-1){
                int pn = p ^ 1;
                if (r == k+1){ rowbuf[pn][c0] = m0; rowbuf[pn][c0+1] = m1; rowbuf[pn][c0+2] = m2; }
                if (k+1 >= c0 && k+1 < c0+3){
                    colbuf[pn][r] = (k+1 == c0) ? m0 : ((k+1 == c0+1) ? m1 : m2);
                }
            }
            __syncthreads();
        }

        // ---- registers now hold G_i: spill (fp32) to workspace, keep fp64 copy ----
        wsG[i*NN + r*48 + c0    ] = make_float2((float)m0.x, (float)m0.y);
        wsG[i*NN + r*48 + c0 + 1] = make_float2((float)m1.x, (float)m1.y);
        wsG[i*NN + r*48 + c0 + 2] = make_float2((float)m2.x, (float)m2.y);
        g0 = m0; g1 = m1; g2 = m2;
    }

    // ================= backward sweep =================
    // i = 47: x_47 = G_47 z_47 (G_47 still in fp64 registers)
    if (t < NXY) tmpv[t] = zv[47*48 + t];
    __syncthreads();
    {
        zplx p = zmul(g0, tmpv[c0]);
        p = zadd(p, zmul(g1, tmpv[c0+1]));
        p = zadd(p, zmul(g2, tmpv[c0+2]));
        psum[r*17 + s] = p;
    }
    __syncthreads();
    if (t < NXY){
        zplx w = psum[t*17];
        #pragma unroll
        for (int q = 1; q < 16; ++q) w = zadd(w, psum[t*17 + q]);
        zv[47*48 + t] = w;
    }
    __syncthreads();

    #pragma unroll 1
    for (int i = NXY-2; i >= 0; --i){
        if (t < NXY) tmpv[t] = zsub(zv[i*48 + t], zmul(hi[i], zv[(i+1)*48 + t]));
        __syncthreads();
        float2 F0 = wsG[i*NN + r*48 + c0    ];
        float2 F1 = wsG[i*NN + r*48 + c0 + 1];
        float2 F2 = wsG[i*NN + r*48 + c0 + 2];
        zplx G0 = make_double2((double)F0.x, (double)F0.y);
        zplx G1 = make_double2((double)F1.x, (double)F1.y);
        zplx G2 = make_double2((double)F2.x, (double)F2.y);
        zplx p = zadd(zadd(zmul(G0, tmpv[c0]), zmul(G1, tmpv[c0+1])), zmul(G2, tmpv[c0+2]));
        psum[r*17 + s] = p;
        __syncthreads();
        if (t < NXY){
            zplx w = psum[t*17];
            #pragma unroll
            for (int q = 1; q < 16; ++q) w = zadd(w, psum[t*17 + q]);
            zv[i*48 + t] = w;
        }
        __syncthreads();
    }

    // ================= epilogue: outputs =================
    // psi_tot[0][alpha][beta][0] = x[beta*48 + alpha] = zv[beta*48 + alpha]
    // channels: 0=err1=psi*y0, 1=err2=psi*y1, 2=en1=y0^2, 3=en2=y1^2
    for (int e = t; e < NN; e += NT){
        int alpha = e / 48, beta = e % 48;
        zplx psi = zv[beta*48 + alpha];
        float pr = (float)psi.x, pi = (float)psi.y;
        float y0 = yaim[2*e], y1 = yaim[2*e + 1];
        if (out_size == NN*4){
            // float32 cast of complex64 ref: REAL parts only, (1,48,48,4)
            float* o = out + 4*e;
            o[0] = pr*y0;
            o[1] = pr*y1;
            o[2] = y0*y0;
            o[3] = y1*y1;
        } else {
            // interleaved (re,im) float32 pairs, (1,48,48,4) complex64
            float* o = out + 8*e;
            o[0] = pr*y0; o[1] = pi*y0;
            o[2] = pr*y1; o[3] = pi*y1;
            o[4] = y0*y0; o[5] = 0.0f;
            o[6] = y1*y1; o[7] = 0.0f;
        }
    }
}

extern "C" void kernel_launch(void* const* d_in, const int* in_sizes, int n_in,
                              void* d_out, int out_size, void* d_ws, size_t ws_size,
                              hipStream_t stream) {
    const float* n_pred = (const float*)d_in[0];   // n_prediction (1,48,48,1)
    // d_in[1] = n_predict_allresults  (unused by reference)
    const float* xb     = (const float*)d_in[2];   // x_b (1,48,48,1)
    const float* ya     = (const float*)d_in[3];   // y_aim (1,48,48,2)
    // d_in[4] = simulation_region     (unused by reference)
    float*  out = (float*)d_out;
    float2* wsG = (float2*)d_ws;                   // needs 48*2304*8 = 884736 B

    hipLaunchKernelGGL(helmholtz_solve_kernel, dim3(1), dim3(NT), 0, stream,
                       n_pred, xb, ya, out, out_size, wsG);
}

// Round 4
// 1315.848 us; speedup vs baseline: 4.1422x; 4.1422x over previous
//
#include <hip/hip_runtime.h>

// WaveguideOutputSimulation: 2D Helmholtz + PML solve.
// Block-tridiagonal Thomas, 48 blocks of 48x48. This version: SINGLE WAVE,
// zero-barrier Gauss-Jordan — 8x8 lane grid, each lane owns a 6x6 complex
// fp32 tile in registers; pivot row/col/value broadcast via __shfl (wave-
// synchronous). Pivot loop = kr (runtime, 0..7) x kj (unrolled, 0..5) so all
// register indices are compile-time. R3 fp64/barrier version: 5510 cyc/pivot
// (barrier-bound). fp32 is safe: R1's "fp32 failure" was the output-layout
// bug (fp64 reproduced the identical absmax).

#define NXY 48
#define NN  2304

typedef float2 cplx;
typedef double2 zplx;

__device__ __forceinline__ cplx cmk(float x, float y){ return make_float2(x,y); }
__device__ __forceinline__ cplx cmul(cplx a, cplx b){
    return cmk(fmaf(a.x,b.x,-(a.y*b.y)), fmaf(a.x,b.y, a.y*b.x));
}
__device__ __forceinline__ cplx cadd(cplx a, cplx b){ return cmk(a.x+b.x, a.y+b.y); }
__device__ __forceinline__ cplx csub(cplx a, cplx b){ return cmk(a.x-b.x, a.y-b.y); }
__device__ __forceinline__ cplx cneg(cplx a){ return cmk(-a.x,-a.y); }
// c - a*b
__device__ __forceinline__ cplx cfms(cplx c, cplx a, cplx b){
    float re = fmaf(-a.x, b.x, fmaf( a.y, b.y, c.x));
    float im = fmaf(-a.x, b.y, fmaf(-a.y, b.x, c.y));
    return cmk(re, im);
}
// c + a*b
__device__ __forceinline__ cplx cfma_(cplx c, cplx a, cplx b){
    float re = fmaf(a.x, b.x, fmaf(-a.y, b.y, c.x));
    float im = fmaf(a.x, b.y, fmaf( a.y, b.x, c.y));
    return cmk(re, im);
}
__device__ __forceinline__ cplx cinv(cplx a){
    float s = 1.0f/fmaf(a.x,a.x, a.y*a.y);
    return cmk(a.x*s, -a.y*s);
}
__device__ __forceinline__ cplx shfl_c(cplx v, int lane){
    return cmk(__shfl(v.x, lane), __shfl(v.y, lane));
}
// sum across the 8 lanes sharing lane bits [3:5] (butterfly over bits 0..2)
__device__ __forceinline__ cplx bfly_c(cplx v){
    v.x += __shfl_xor(v.x,1); v.y += __shfl_xor(v.y,1);
    v.x += __shfl_xor(v.x,2); v.y += __shfl_xor(v.y,2);
    v.x += __shfl_xor(v.x,4); v.y += __shfl_xor(v.y,4);
    return v;
}

// ---- fp64 setup math (once per launch, negligible) ----
__device__ __forceinline__ zplx zmul64(zplx a, zplx b){
    return make_double2(a.x*b.x - a.y*b.y, a.x*b.y + a.y*b.x);
}
__device__ __forceinline__ zplx zadd64(zplx a, zplx b){ return make_double2(a.x+b.x, a.y+b.y); }
__device__ __forceinline__ zplx zneg64(zplx a){ return make_double2(-a.x, -a.y); }
__device__ __forceinline__ zplx zinv64(zplx a){
    double s = 1.0/(a.x*a.x + a.y*a.y);
    return make_double2(a.x*s, -a.y*s);
}
__device__ __forceinline__ zplx fun_s(double u){
    const double sig = 0.8*4.0*40.0/(2.0*3.1415926);
    double u3 = u*u*u;
    return make_double2(1.0 + 14.0*u3, sig*u3);
}
__device__ __forceinline__ zplx s_half_at(int j){
    if (j <= 8)  return fun_s((8.5 - (double)j)/9.0);
    if (j >= 40) return fun_s(((double)(j-40) + 0.5)/9.0);
    return make_double2(1.0, 0.0);
}
__device__ __forceinline__ zplx s_int_at(int j){
    if (j <= 7)  return fun_s((8.0 - (double)j)/9.0);
    if (j >= 40) return fun_s(((double)(j-40) + 1.0)/9.0);
    return make_double2(1.0, 0.0);
}

__global__ __launch_bounds__(64,1) void helm_wave(
    const float* __restrict__ n_pred,   // (1,48,48,1)
    const float* __restrict__ xb,       // (1,48,48,1)
    const float* __restrict__ yaim,     // (1,48,48,2)
    float*       __restrict__ out,
    int                       out_size,
    float2*      __restrict__ wsG)      // 48*2304 float2 G history
{
    __shared__ cplx dgv[NXY], lov[NXY], hiv[NXY];
    __shared__ float nk[NN];            // k^2 n^2 at [iy*48+ix]
    __shared__ float bb[NN];            // b at [iy*48+ix]
    __shared__ cplx zv[NN];             // z (fwd) then x (bwd), for epilogue

    const int t  = threadIdx.x;         // single wave: 0..63
    const int lr = t>>3, lc = t&7;      // 8x8 lane grid
    const int r0 = 6*lr, c0v = 6*lc;    // this lane: rows r0..r0+5, cols c0v..c0v+5
    const int diagl = (lc<<3)|lc;       // diagonal lane of my column-group
    const double k2 = 0.2026833935483871*0.2026833935483871;

    // ---- setup tridiagonal L (fp64 -> fp32) ----
    if (t < NXY){
        int a = t;
        zplx isha  = zinv64(s_half_at(a));
        zplx isha1 = zinv64(s_half_at(a+1));
        zplx isi   = zinv64(s_int_at(a));
        zplx dgd = zneg64(zmul64(isi, zadd64(isha,isha1)));
        zplx lod = zmul64(isi, isha);
        zplx hid = zmul64(isi, isha1);
        dgv[a] = cmk((float)dgd.x,(float)dgd.y);
        lov[a] = cmk((float)lod.x,(float)lod.y);
        hiv[a] = cmk((float)hid.x,(float)hid.y);
    }
    for (int e=t; e<NN; e+=64){
        int i_=e/48, a_=e%48;           // [iy*48+ix] <- input [ix*48+iy]
        float nv = n_pred[a_*48+i_];
        nk[e] = (float)(k2*(double)nv*(double)nv);
        bb[e] = xb[a_*48+i_];
    }
    __syncthreads();

    cplx g[6][6];                        // G_{i-1}
    cplx m[6][6];                        // S_i -> G_i
    cplx zrow[6];                        // z_i at my rows (valid in all lanes)
    #pragma unroll
    for (int i=0;i<6;++i) zrow[i] = cmk(0.f,0.f);

    // ================= forward sweep =================
    #pragma unroll 1
    for (int ib=0; ib<NXY; ++ib){
        // z_{ib-1} at my columns (from diagonal lane of my col-group)
        cplx zc[6];
        #pragma unroll
        for (int j=0;j<6;++j) zc[j] = shfl_c(zrow[j], diagl);

        cplx ci = (ib>0)? cmul(lov[ib], hiv[ib-1]) : cmk(0.f,0.f);
        bool same  = (lc==lr), right = (lc==lr+1), left = (lc+1==lr);
        cplx p[6];
        #pragma unroll
        for (int i=0;i<6;++i){
            int r = r0+i;
            cplx dgr = dgv[r], lor = lov[r], hir = hiv[r];
            cplx ddi = cadd(cadd(dgv[ib], dgr), cmk(nk[ib*48+r],0.f));
            cplx acc = cmk(0.f,0.f);
            #pragma unroll
            for (int j=0;j<6;++j){
                cplx v = (ib>0)? cneg(cmul(ci, g[i][j])) : cmk(0.f,0.f);
                if (same){
                    if (j==i)   v = cadd(v, ddi);
                    if (j==i+1) v = cadd(v, hir);
                    if (j+1==i) v = cadd(v, lor);
                }
                if (right && i==5 && j==0) v = cadd(v, hir);
                if (left  && i==0 && j==5) v = cadd(v, lor);
                m[i][j] = v;
                if (ib>0) acc = cfma_(acc, g[i][j], zc[j]);
            }
            p[i] = acc;
        }
        // z_ib = b_ib - lo_ib * (G_{ib-1} z_{ib-1})
        if (ib>0){
            cplx loib = lov[ib];
            #pragma unroll
            for (int i=0;i<6;++i){
                cplx w = bfly_c(p[i]);
                zrow[i] = cfms(cmk(bb[ib*48+r0+i],0.f), loib, w);
            }
        } else {
            #pragma unroll
            for (int i=0;i<6;++i) zrow[i] = cmk(bb[r0+i], 0.f);
        }
        if (lc==0){
            #pragma unroll
            for (int i=0;i<6;++i) zv[ib*48+r0+i] = zrow[i];
        }

        // ---- zero-barrier Gauss-Jordan: 48 pivots via shuffles ----
        #pragma unroll 1
        for (int kr=0; kr<8; ++kr){
            bool prow = (lr==kr), pcol = (lc==kr);
            int rsrc = (kr<<3)|lc;      // lane holding pivot-row seg for my cols
            int csrc = (lr<<3)|kr;      // lane holding pivot-col seg for my rows
            int dsrc = (kr<<3)|kr;      // lane holding the pivot element
            #pragma unroll
            for (int kj=0;kj<6;++kj){
                cplx pv = shfl_c(m[kj][kj], dsrc);
                cplx d  = cinv(pv);
                cplx rs[6], cs[6];
                #pragma unroll
                for (int j=0;j<6;++j) rs[j] = shfl_c(m[kj][j], rsrc);
                #pragma unroll
                for (int i=0;i<6;++i) cs[i] = shfl_c(m[i][kj], csrc);
                cplx rsp[6];
                #pragma unroll
                for (int j=0;j<6;++j) rsp[j] = cmul(d, rs[j]);
                cplx u[6];
                #pragma unroll
                for (int i=0;i<6;++i) u[i] = cs[i];
                if (prow) u[kj] = csub(pv, cmk(1.f,0.f)); // makes row k -> d*row k
                #pragma unroll
                for (int i=0;i<6;++i){
                    #pragma unroll
                    for (int j=0;j<6;++j){
                        m[i][j] = cfms(m[i][j], u[i], rsp[j]);
                    }
                }
                if (pcol){  // pivot column -> -d*old_col (and pivot elem -> d)
                    #pragma unroll
                    for (int i=0;i<6;++i) m[i][kj] = cneg(cmul(d, cs[i]));
                    if (prow) m[kj][kj] = d;
                }
            }
        }

        // spill G_ib for backward sweep; keep as g
        #pragma unroll
        for (int i=0;i<6;++i){
            #pragma unroll
            for (int j=0;j<6;++j){
                wsG[ib*NN + (r0+i)*48 + c0v + j] = m[i][j];
                g[i][j] = m[i][j];
            }
        }
    }

    // ================= backward sweep =================
    cplx xrow[6];
    {   // x_47 = G_47 z_47  (g == G_47, zrow == z_47)
        cplx zc[6];
        #pragma unroll
        for (int j=0;j<6;++j) zc[j] = shfl_c(zrow[j], diagl);
        #pragma unroll
        for (int i=0;i<6;++i){
            cplx acc = cmk(0.f,0.f);
            #pragma unroll
            for (int j=0;j<6;++j) acc = cfma_(acc, g[i][j], zc[j]);
            xrow[i] = bfly_c(acc);
        }
        if (lc==0){
            #pragma unroll
            for (int i=0;i<6;++i) zv[47*48+r0+i] = xrow[i];
        }
    }
    __syncthreads();

    #pragma unroll 1
    for (int ib=NXY-2; ib>=0; --ib){
        cplx xc[6], tm[6];
        #pragma unroll
        for (int j=0;j<6;++j) xc[j] = shfl_c(xrow[j], diagl);
        cplx hiib = hiv[ib];
        #pragma unroll
        for (int j=0;j<6;++j) tm[j] = cfms(zv[ib*48+c0v+j], hiib, xc[j]);
        #pragma unroll
        for (int i=0;i<6;++i){
            cplx acc = cmk(0.f,0.f);
            #pragma unroll
            for (int j=0;j<6;++j){
                cplx Gv = wsG[ib*NN + (r0+i)*48 + c0v + j];
                acc = cfma_(acc, Gv, tm[j]);
            }
            xrow[i] = bfly_c(acc);
        }
        if (lc==0){
            #pragma unroll
            for (int i=0;i<6;++i) zv[ib*48+r0+i] = xrow[i];
        }
    }
    __syncthreads();

    // ================= epilogue =================
    // psi_tot[0][alpha][beta] = x[beta*48+alpha]; out real-parts (1,48,48,4)
    for (int e=t; e<NN; e+=64){
        int alpha=e/48, beta=e%48;
        cplx psi = zv[beta*48+alpha];
        float y0=yaim[2*e], y1=yaim[2*e+1];
        if (out_size == NN*4){
            float4 o = make_float4(psi.x*y0, psi.x*y1, y0*y0, y1*y1);
            *(float4*)(out + 4*e) = o;
        } else {
            float* o = out + 8*e;
            o[0]=psi.x*y0; o[1]=psi.y*y0; o[2]=psi.x*y1; o[3]=psi.y*y1;
            o[4]=y0*y0; o[5]=0.f; o[6]=y1*y1; o[7]=0.f;
        }
    }
}

extern "C" void kernel_launch(void* const* d_in, const int* in_sizes, int n_in,
                              void* d_out, int out_size, void* d_ws, size_t ws_size,
                              hipStream_t stream) {
    const float* n_pred = (const float*)d_in[0];   // n_prediction
    const float* xb     = (const float*)d_in[2];   // x_b
    const float* ya     = (const float*)d_in[3];   // y_aim
    float*  out = (float*)d_out;
    float2* wsG = (float2*)d_ws;                   // 48*2304*8 = 884736 B

    hipLaunchKernelGGL(helm_wave, dim3(1), dim3(64), 0, stream,
                       n_pred, xb, ya, out, out_size, wsG);
}

// Round 5
// 745.309 us; speedup vs baseline: 7.3130x; 1.7655x over previous
//
#include <hip/hip_runtime.h>

// WaveguideOutputSimulation: 2D Helmholtz + PML solve.
// Block-tridiagonal system, 48 blocks of 48x48, scalar off-diagonal blocks.
// R5: BABE (two-sided block Thomas). Wave 0 eliminates blocks 0..23 (+forms
// S_24), wave 1 eliminates 47..25, in parallel on separate SIMDs; interface
// F = S_24 - u24*l25*H_25 inverted by wave 0 (H_25 passed via LDS); both
// back-substitutions run in parallel. Each wave: zero-barrier Gauss-Jordan,
// 8x8 lane grid, 6x6 complex fp32 tile per lane, pivot row/col/value via
// __shfl. Serial inversion depth 48 -> 25.

#define NXY 48
#define NN  2304

typedef float2 cplx;
typedef double2 zplx;

__device__ __forceinline__ cplx cmk(float x, float y){ return make_float2(x,y); }
__device__ __forceinline__ cplx cmul(cplx a, cplx b){
    return cmk(fmaf(a.x,b.x,-(a.y*b.y)), fmaf(a.x,b.y, a.y*b.x));
}
__device__ __forceinline__ cplx cadd(cplx a, cplx b){ return cmk(a.x+b.x, a.y+b.y); }
__device__ __forceinline__ cplx csub(cplx a, cplx b){ return cmk(a.x-b.x, a.y-b.y); }
__device__ __forceinline__ cplx cneg(cplx a){ return cmk(-a.x,-a.y); }
// c - a*b
__device__ __forceinline__ cplx cfms(cplx c, cplx a, cplx b){
    float re = fmaf(-a.x, b.x, fmaf( a.y, b.y, c.x));
    float im = fmaf(-a.x, b.y, fmaf(-a.y, b.x, c.y));
    return cmk(re, im);
}
// c + a*b
__device__ __forceinline__ cplx cfma_(cplx c, cplx a, cplx b){
    float re = fmaf(a.x, b.x, fmaf(-a.y, b.y, c.x));
    float im = fmaf(a.x, b.y, fmaf( a.y, b.x, c.y));
    return cmk(re, im);
}
__device__ __forceinline__ cplx cinv(cplx a){
    float s = 1.0f/fmaf(a.x,a.x, a.y*a.y);
    return cmk(a.x*s, -a.y*s);
}
__device__ __forceinline__ cplx shfl_c(cplx v, int lane){
    return cmk(__shfl(v.x, lane), __shfl(v.y, lane));
}
// sum across the 8 lanes sharing lane bits [3:5] (butterfly over bits 0..2)
__device__ __forceinline__ cplx bfly_c(cplx v){
    v.x += __shfl_xor(v.x,1); v.y += __shfl_xor(v.y,1);
    v.x += __shfl_xor(v.x,2); v.y += __shfl_xor(v.y,2);
    v.x += __shfl_xor(v.x,4); v.y += __shfl_xor(v.y,4);
    return v;
}

// ---- fp64 setup math (once per launch, negligible) ----
__device__ __forceinline__ zplx zmul64(zplx a, zplx b){
    return make_double2(a.x*b.x - a.y*b.y, a.x*b.y + a.y*b.x);
}
__device__ __forceinline__ zplx zadd64(zplx a, zplx b){ return make_double2(a.x+b.x, a.y+b.y); }
__device__ __forceinline__ zplx zneg64(zplx a){ return make_double2(-a.x, -a.y); }
__device__ __forceinline__ zplx zinv64(zplx a){
    double s = 1.0/(a.x*a.x + a.y*a.y);
    return make_double2(a.x*s, -a.y*s);
}
__device__ __forceinline__ zplx fun_s(double u){
    const double sig = 0.8*4.0*40.0/(2.0*3.1415926);
    double u3 = u*u*u;
    return make_double2(1.0 + 14.0*u3, sig*u3);
}
__device__ __forceinline__ zplx s_half_at(int j){
    if (j <= 8)  return fun_s((8.5 - (double)j)/9.0);
    if (j >= 40) return fun_s(((double)(j-40) + 0.5)/9.0);
    return make_double2(1.0, 0.0);
}
__device__ __forceinline__ zplx s_int_at(int j){
    if (j <= 7)  return fun_s((8.0 - (double)j)/9.0);
    if (j >= 40) return fun_s(((double)(j-40) + 1.0)/9.0);
    return make_double2(1.0, 0.0);
}

// Zero-barrier in-wave Gauss-Jordan inversion of the distributed 48x48
// (8x8 lanes x 6x6 tile). All register indices compile-time.
__device__ __forceinline__ void gj48(cplx (&m)[6][6], int lr, int lc){
    #pragma unroll 1
    for (int kr=0; kr<8; ++kr){
        bool prow = (lr==kr), pcol = (lc==kr);
        int rsrc = (kr<<3)|lc;
        int csrc = (lr<<3)|kr;
        int dsrc = (kr<<3)|kr;
        #pragma unroll
        for (int kj=0;kj<6;++kj){
            cplx pv = shfl_c(m[kj][kj], dsrc);
            cplx d  = cinv(pv);
            cplx rs[6], cs[6];
            #pragma unroll
            for (int j=0;j<6;++j) rs[j] = shfl_c(m[kj][j], rsrc);
            #pragma unroll
            for (int i=0;i<6;++i) cs[i] = shfl_c(m[i][kj], csrc);
            cplx rsp[6];
            #pragma unroll
            for (int j=0;j<6;++j) rsp[j] = cmul(d, rs[j]);
            cplx u[6];
            #pragma unroll
            for (int i=0;i<6;++i) u[i] = cs[i];
            if (prow) u[kj] = csub(pv, cmk(1.f,0.f));
            #pragma unroll
            for (int i=0;i<6;++i){
                #pragma unroll
                for (int j=0;j<6;++j) m[i][j] = cfms(m[i][j], u[i], rsp[j]);
            }
            if (pcol){
                #pragma unroll
                for (int i=0;i<6;++i) m[i][kj] = cneg(cmul(d, cs[i]));
                if (prow) m[kj][kj] = d;
            }
        }
    }
}

__global__ __launch_bounds__(128,1) void helm_babe(
    const float* __restrict__ n_pred,
    const float* __restrict__ xb,
    const float* __restrict__ yaim,
    float*       __restrict__ out,
    int                       out_size,
    float2*      __restrict__ wsG)
{
    __shared__ cplx dgv[NXY], lov[NXY], hiv[NXY];
    __shared__ float nk[NN];            // k^2 n^2 at [iy*48+ix]
    __shared__ float bb[NN];            // b at [iy*48+ix]
    __shared__ cplx zv[NN];             // z/w (fwd) then x, per block
    __shared__ cplx Hx[NN];             // H_25 exchange (wave1 -> wave0)
    __shared__ cplx vv[NXY];            // H_25 * w_25

    const int t    = threadIdx.x;
    const int lane = t & 63;
    const int wid  = t >> 6;            // 0: top sweep, 1: bottom sweep
    const int lr = lane>>3, lc = lane&7;
    const int r0 = 6*lr, c0v = 6*lc;
    const int diagl = (lc<<3)|lc;
    const double k2 = 0.2026833935483871*0.2026833935483871;

    // ---- setup tridiagonal L (fp64 -> fp32) ----
    if (t < NXY){
        int a = t;
        zplx isha  = zinv64(s_half_at(a));
        zplx isha1 = zinv64(s_half_at(a+1));
        zplx isi   = zinv64(s_int_at(a));
        zplx dgd = zneg64(zmul64(isi, zadd64(isha,isha1)));
        zplx lod = zmul64(isi, isha);
        zplx hid = zmul64(isi, isha1);
        dgv[a] = cmk((float)dgd.x,(float)dgd.y);
        lov[a] = cmk((float)lod.x,(float)lod.y);
        hiv[a] = cmk((float)hid.x,(float)hid.y);
    }
    for (int e=t; e<NN; e+=128){
        int i_=e/48, a_=e%48;           // [iy*48+ix] <- input [ix*48+iy]
        float nv = n_pred[a_*48+i_];
        nk[e] = (float)(k2*(double)nv*(double)nv);
        bb[e] = xb[a_*48+i_];
    }
    __syncthreads();

    const int dir    = (wid==0) ? 1 : -1;
    const int ibeg   = (wid==0) ? 0 : 47;
    const int nsteps = (wid==0) ? 25 : 23;   // wave0 step 24 = partial (S_24 only)

    cplx g[6][6];
    cplx m[6][6];
    cplx zrow[6];
    #pragma unroll
    for (int i=0;i<6;++i) zrow[i] = cmk(0.f,0.f);

    // ================= two-sided forward elimination =================
    #pragma unroll 1
    for (int step=0; step<nsteps; ++step){
        int ib = ibeg + dir*step;
        bool full = !(wid==0 && step==24);

        cplx zc[6];
        #pragma unroll
        for (int j=0;j<6;++j) zc[j] = shfl_c(zrow[j], diagl);

        cplx ci = cmk(0.f,0.f), czp = cmk(0.f,0.f);
        if (step>0){
            if (dir>0){ ci = cmul(lov[ib], hiv[ib-1]); czp = lov[ib]; }
            else      { ci = cmul(hiv[ib], lov[ib+1]); czp = hiv[ib]; }
        }
        bool same  = (lc==lr), rightn = (lc==lr+1), leftn = (lc+1==lr);
        cplx p[6];
        #pragma unroll
        for (int i=0;i<6;++i){
            int r = r0+i;
            cplx dgr = dgv[r], lor = lov[r], hir = hiv[r];
            cplx ddi = cadd(cadd(dgv[ib], dgr), cmk(nk[ib*48+r],0.f));
            cplx acc = cmk(0.f,0.f);
            #pragma unroll
            for (int j=0;j<6;++j){
                cplx v = (step>0)? cneg(cmul(ci, g[i][j])) : cmk(0.f,0.f);
                if (same){
                    if (j==i)   v = cadd(v, ddi);
                    if (j==i+1) v = cadd(v, hir);
                    if (j+1==i) v = cadd(v, lor);
                }
                if (rightn && i==5 && j==0) v = cadd(v, hir);
                if (leftn  && i==0 && j==5) v = cadd(v, lor);
                m[i][j] = v;
                if (step>0) acc = cfma_(acc, g[i][j], zc[j]);
            }
            p[i] = acc;
        }
        if (step>0){
            #pragma unroll
            for (int i=0;i<6;++i){
                cplx w = bfly_c(p[i]);
                zrow[i] = cfms(cmk(bb[ib*48+r0+i],0.f), czp, w);
            }
        } else {
            #pragma unroll
            for (int i=0;i<6;++i) zrow[i] = cmk(bb[ib*48+r0+i], 0.f);
        }
        if (lc==0){
            #pragma unroll
            for (int i=0;i<6;++i) zv[ib*48+r0+i] = zrow[i];
        }

        if (full){
            gj48(m, lr, lc);
            if (ib == 25){
                // hand H_25 to wave 0 via LDS (skip global spill)
                #pragma unroll
                for (int i=0;i<6;++i)
                    #pragma unroll
                    for (int j=0;j<6;++j) Hx[(r0+i)*48 + c0v + j] = m[i][j];
            } else {
                #pragma unroll
                for (int i=0;i<6;++i)
                    #pragma unroll
                    for (int j=0;j<6;++j) wsG[ib*NN + (r0+i)*48 + c0v + j] = m[i][j];
            }
            #pragma unroll
            for (int i=0;i<6;++i)
                #pragma unroll
                for (int j=0;j<6;++j) g[i][j] = m[i][j];
        }
    }

    // wave 1: v = H_25 * w_25 into LDS
    if (wid==1){
        cplx zc[6];
        #pragma unroll
        for (int j=0;j<6;++j) zc[j] = shfl_c(zrow[j], diagl);
        #pragma unroll
        for (int i=0;i<6;++i){
            cplx acc = cmk(0.f,0.f);
            #pragma unroll
            for (int j=0;j<6;++j) acc = cfma_(acc, m[i][j], zc[j]);
            acc = bfly_c(acc);
            if (lc==0) vv[r0+i] = acc;
        }
    }
    __syncthreads();

    // ================= interface (wave 0) =================
    cplx xrow[6];
    if (wid==0){
        // m = S_24, zrow = z_24 (valid all lanes)
        cplx cf = cmul(hiv[24], lov[25]);
        #pragma unroll
        for (int i=0;i<6;++i)
            #pragma unroll
            for (int j=0;j<6;++j) m[i][j] = cfms(m[i][j], cf, Hx[(r0+i)*48 + c0v + j]);
        #pragma unroll
        for (int i=0;i<6;++i) zrow[i] = cfms(zrow[i], hiv[24], vv[r0+i]);
        gj48(m, lr, lc);    // m = F^{-1}
        // x_24 = F^{-1} * rhs
        cplx zc[6];
        #pragma unroll
        for (int j=0;j<6;++j) zc[j] = shfl_c(zrow[j], diagl);
        #pragma unroll
        for (int i=0;i<6;++i){
            cplx acc = cmk(0.f,0.f);
            #pragma unroll
            for (int j=0;j<6;++j) acc = cfma_(acc, m[i][j], zc[j]);
            xrow[i] = bfly_c(acc);
        }
        if (lc==0){
            #pragma unroll
            for (int i=0;i<6;++i) zv[24*48+r0+i] = xrow[i];
        }
        // x_25 = H_25 (w_25 - lov[25] x_24)
        cplx xc[6], tm[6];
        #pragma unroll
        for (int j=0;j<6;++j) xc[j] = shfl_c(xrow[j], diagl);
        #pragma unroll
        for (int j=0;j<6;++j) tm[j] = cfms(zv[25*48+c0v+j], lov[25], xc[j]);
        #pragma unroll
        for (int i=0;i<6;++i){
            cplx acc = cmk(0.f,0.f);
            #pragma unroll
            for (int j=0;j<6;++j) acc = cfma_(acc, Hx[(r0+i)*48 + c0v + j], tm[j]);
            acc = bfly_c(acc);
            if (lc==0) zv[25*48+r0+i] = acc;
        }
    }
    __syncthreads();

    // ================= parallel back-substitution =================
    if (wid==0){
        // xrow = x_24; descend 23..0: x_i = G_i (z_i - hiv[i] x_{i+1})
        #pragma unroll 1
        for (int ib=23; ib>=0; --ib){
            cplx xc[6], tm[6];
            #pragma unroll
            for (int j=0;j<6;++j) xc[j] = shfl_c(xrow[j], diagl);
            cplx hiib = hiv[ib];
            #pragma unroll
            for (int j=0;j<6;++j) tm[j] = cfms(zv[ib*48+c0v+j], hiib, xc[j]);
            #pragma unroll
            for (int i=0;i<6;++i){
                cplx acc = cmk(0.f,0.f);
                #pragma unroll
                for (int j=0;j<6;++j){
                    cplx Gv = wsG[ib*NN + (r0+i)*48 + c0v + j];
                    acc = cfma_(acc, Gv, tm[j]);
                }
                xrow[i] = bfly_c(acc);
            }
            if (lc==0){
                #pragma unroll
                for (int i=0;i<6;++i) zv[ib*48+r0+i] = xrow[i];
            }
        }
    } else {
        // xrow = x_25 (from LDS); ascend 26..47: x_i = H_i (w_i - lov[i] x_{i-1})
        #pragma unroll
        for (int i=0;i<6;++i) xrow[i] = zv[25*48+r0+i];
        #pragma unroll 1
        for (int ib=26; ib<NXY; ++ib){
            cplx xc[6], tm[6];
            #pragma unroll
            for (int j=0;j<6;++j) xc[j] = shfl_c(xrow[j], diagl);
            cplx loib = lov[ib];
            #pragma unroll
            for (int j=0;j<6;++j) tm[j] = cfms(zv[ib*48+c0v+j], loib, xc[j]);
            #pragma unroll
            for (int i=0;i<6;++i){
                cplx acc = cmk(0.f,0.f);
                #pragma unroll
                for (int j=0;j<6;++j){
                    cplx Gv = wsG[ib*NN + (r0+i)*48 + c0v + j];
                    acc = cfma_(acc, Gv, tm[j]);
                }
                xrow[i] = bfly_c(acc);
            }
            if (lc==0){
                #pragma unroll
                for (int i=0;i<6;++i) zv[ib*48+r0+i] = xrow[i];
            }
        }
    }
    __syncthreads();

    // ================= epilogue =================
    // psi_tot[0][alpha][beta] = x[beta*48+alpha]; out real-parts (1,48,48,4)
    for (int e=t; e<NN; e+=128){
        int alpha=e/48, beta=e%48;
        cplx psi = zv[beta*48+alpha];
        float y0=yaim[2*e], y1=yaim[2*e+1];
        if (out_size == NN*4){
            float4 o = make_float4(psi.x*y0, psi.x*y1, y0*y0, y1*y1);
            *(float4*)(out + 4*e) = o;
        } else {
            float* o = out + 8*e;
            o[0]=psi.x*y0; o[1]=psi.y*y0; o[2]=psi.x*y1; o[3]=psi.y*y1;
            o[4]=y0*y0; o[5]=0.f; o[6]=y1*y1; o[7]=0.f;
        }
    }
}

extern "C" void kernel_launch(void* const* d_in, const int* in_sizes, int n_in,
                              void* d_out, int out_size, void* d_ws, size_t ws_size,
                              hipStream_t stream) {
    const float* n_pred = (const float*)d_in[0];   // n_prediction
    const float* xb     = (const float*)d_in[2];   // x_b
    const float* ya     = (const float*)d_in[3];   // y_aim
    float*  out = (float*)d_out;
    float2* wsG = (float2*)d_ws;                   // 48*2304*8 = 884736 B

    hipLaunchKernelGGL(helm_babe, dim3(1), dim3(128), 0, stream,
                       n_pred, xb, ya, out, out_size, wsG);
}

// Round 6
// 615.516 us; speedup vs baseline: 8.8551x; 1.2109x over previous
//
#include <hip/hip_runtime.h>

// WaveguideOutputSimulation: 2D Helmholtz + PML solve.
// BABE block-Thomas (2 waves, serial depth 25). R6: software-pipelined
// zero-barrier Gauss-Jordan with uniform-update identity (u[kj]=pv-1 on
// pivot-row lanes, rsp[kj]=1+d on pivot-col lanes => one rank-1 update does
// the whole in-place pivot incl. fixups), lookahead shuffles for the next
// pivot issued before the bulk update, packed-fp32 complex math
// (ext_vector float2 + __builtin_elementwise_fma -> v_pk_fma_f32), and
// float4-packed G spill/reload.

#define NXY 48
#define NN  2304

typedef float v2 __attribute__((ext_vector_type(2)));
typedef double2 zplx;

__device__ __forceinline__ v2 mk2(float x, float y){ v2 r; r.x=x; r.y=y; return r; }
__device__ __forceinline__ v2 bcx(v2 a){ return __builtin_shufflevector(a,a,0,0); }
__device__ __forceinline__ v2 bcy(v2 a){ return __builtin_shufflevector(a,a,1,1); }
// (-a.y, a.x)
__device__ __forceinline__ v2 jswp(v2 a){ v2 r = __builtin_shufflevector(a,a,1,0); r.x = -r.x; return r; }
// a*b (complex) = a.x*(b.x,b.y) + a.y*(-b.y,b.x)
__device__ __forceinline__ v2 cmul(v2 a, v2 b){
    return __builtin_elementwise_fma(bcx(a), b, bcy(a)*jswp(b));
}
// c + a*b
__device__ __forceinline__ v2 cfma_(v2 c, v2 a, v2 b){
    return __builtin_elementwise_fma(bcx(a), b, __builtin_elementwise_fma(bcy(a), jswp(b), c));
}
// c - a*b
__device__ __forceinline__ v2 cfms(v2 c, v2 a, v2 b){
    return __builtin_elementwise_fma(-bcx(a), b, __builtin_elementwise_fma(-bcy(a), jswp(b), c));
}
__device__ __forceinline__ v2 cinv(v2 a){
    float s = 1.0f/fmaf(a.x,a.x, a.y*a.y);
    return mk2(a.x*s, -a.y*s);
}
__device__ __forceinline__ v2 shfl_c(v2 a, int lane){
    return mk2(__shfl(a.x, lane), __shfl(a.y, lane));
}
__device__ __forceinline__ v2 bfly_c(v2 v){
    v.x += __shfl_xor(v.x,1); v.y += __shfl_xor(v.y,1);
    v.x += __shfl_xor(v.x,2); v.y += __shfl_xor(v.y,2);
    v.x += __shfl_xor(v.x,4); v.y += __shfl_xor(v.y,4);
    return v;
}

// ---- fp64 setup math (once per launch, negligible) ----
__device__ __forceinline__ zplx zmul64(zplx a, zplx b){
    return make_double2(a.x*b.x - a.y*b.y, a.x*b.y + a.y*b.x);
}
__device__ __forceinline__ zplx zadd64(zplx a, zplx b){ return make_double2(a.x+b.x, a.y+b.y); }
__device__ __forceinline__ zplx zneg64(zplx a){ return make_double2(-a.x, -a.y); }
__device__ __forceinline__ zplx zinv64(zplx a){
    double s = 1.0/(a.x*a.x + a.y*a.y);
    return make_double2(a.x*s, -a.y*s);
}
__device__ __forceinline__ zplx fun_s(double u){
    const double sig = 0.8*4.0*40.0/(2.0*3.1415926);
    double u3 = u*u*u;
    return make_double2(1.0 + 14.0*u3, sig*u3);
}
__device__ __forceinline__ zplx s_half_at(int j){
    if (j <= 8)  return fun_s((8.5 - (double)j)/9.0);
    if (j >= 40) return fun_s(((double)(j-40) + 0.5)/9.0);
    return make_double2(1.0, 0.0);
}
__device__ __forceinline__ zplx s_int_at(int j){
    if (j <= 7)  return fun_s((8.0 - (double)j)/9.0);
    if (j >= 40) return fun_s(((double)(j-40) + 1.0)/9.0);
    return make_double2(1.0, 0.0);
}

// Software-pipelined zero-barrier in-wave Gauss-Jordan of the distributed
// 48x48 (8x8 lanes x 6x6 tile). Uniform-update identity: with
// u[kj]=pv-1 (pivot-row lanes) and rsp[kj]=1+d (pivot-col lanes), the single
// rank-1 update m[i][j] -= u[i]*rsp[j] performs the complete in-place pivot:
//   general: m - cs*d*rs ; pivot row -> d*row ; pivot col -> -d*col ; pivot -> d.
// Next pivot's row/col (tile index nj) updated first, then its shuffles are
// issued, then the remaining 25 elements update under the shuffle latency.
__device__ __forceinline__ void gj48(v2 (&m)[6][6], const int lr, const int lc){
    v2 pv, rs[6], cs[6];
    {
        const int rsrc0 = lc, csrc0 = (lr<<3);
        pv = shfl_c(m[0][0], 0);
        #pragma unroll
        for (int j=0;j<6;++j) rs[j] = shfl_c(m[0][j], rsrc0);
        #pragma unroll
        for (int i=0;i<6;++i) cs[i] = shfl_c(m[i][0], csrc0);
    }
    #pragma unroll 1
    for (int kr=0; kr<8; ++kr){
        const bool prow = (lr==kr), pcol = (lc==kr);
        #pragma unroll
        for (int kj=0; kj<6; ++kj){
            const int nj = (kj+1)%6;                       // compile-time
            const int cr = (kj==5) ? ((kr<7)?(kr+1):7) : kr;
            const int nrsrc = (cr<<3)|lc;
            const int ncsrc = (lr<<3)|cr;
            const int ndsrc = (cr<<3)|cr;
            v2 d = cinv(pv);
            v2 rsp[6];
            #pragma unroll
            for (int j=0;j<6;++j) rsp[j] = cmul(d, rs[j]);
            if (pcol) rsp[kj] = d + mk2(1.f,0.f);
            v2 u[6];
            #pragma unroll
            for (int i=0;i<6;++i) u[i] = cs[i];
            if (prow) u[kj] = pv - mk2(1.f,0.f);
            // early update: row nj and column nj (gate the next pivot)
            #pragma unroll
            for (int j=0;j<6;++j) m[nj][j] = cfms(m[nj][j], u[nj], rsp[j]);
            #pragma unroll
            for (int i=0;i<6;++i){ if (i!=nj) m[i][nj] = cfms(m[i][nj], u[i], rsp[nj]); }
            // issue next pivot's shuffles now
            v2 npv = shfl_c(m[nj][nj], ndsrc);
            v2 nrs[6], ncs[6];
            #pragma unroll
            for (int j=0;j<6;++j) nrs[j] = shfl_c(m[nj][j], nrsrc);
            #pragma unroll
            for (int i=0;i<6;++i) ncs[i] = shfl_c(m[i][nj], ncsrc);
            // bulk update under the shuffle latency
            #pragma unroll
            for (int i=0;i<6;++i){
                if (i==nj) continue;
                #pragma unroll
                for (int j=0;j<6;++j){
                    if (j==nj) continue;
                    m[i][j] = cfms(m[i][j], u[i], rsp[j]);
                }
            }
            pv = npv;
            #pragma unroll
            for (int j=0;j<6;++j){ rs[j]=nrs[j]; cs[j]=ncs[j]; }
        }
    }
}

__global__ __launch_bounds__(128,1) void helm_babe(
    const float* __restrict__ n_pred,
    const float* __restrict__ xb,
    const float* __restrict__ yaim,
    float*       __restrict__ out,
    int                       out_size,
    float*       __restrict__ wsG)      // 48*2304 cplx (float pairs) G history
{
    __shared__ v2 dgv[NXY], lov[NXY], hiv[NXY];
    __shared__ float nk[NN];            // k^2 n^2 at [iy*48+ix]
    __shared__ float bb[NN];            // b at [iy*48+ix]
    __shared__ v2 zv[NN];               // z/w (fwd) then x, per block
    __shared__ v2 Hx[NN];               // H_25 exchange (wave1 -> wave0)
    __shared__ v2 vv[NXY];              // H_25 * w_25

    const int t    = threadIdx.x;
    const int lane = t & 63;
    const int wid  = t >> 6;            // 0: top sweep, 1: bottom sweep
    const int lr = lane>>3, lc = lane&7;
    const int r0 = 6*lr, c0v = 6*lc;
    const int diagl = (lc<<3)|lc;
    const double k2 = 0.2026833935483871*0.2026833935483871;

    // ---- setup tridiagonal L (fp64 -> fp32) ----
    if (t < NXY){
        int a = t;
        zplx isha  = zinv64(s_half_at(a));
        zplx isha1 = zinv64(s_half_at(a+1));
        zplx isi   = zinv64(s_int_at(a));
        zplx dgd = zneg64(zmul64(isi, zadd64(isha,isha1)));
        zplx lod = zmul64(isi, isha);
        zplx hid = zmul64(isi, isha1);
        dgv[a] = mk2((float)dgd.x,(float)dgd.y);
        lov[a] = mk2((float)lod.x,(float)lod.y);
        hiv[a] = mk2((float)hid.x,(float)hid.y);
    }
    for (int e=t; e<NN; e+=128){
        int i_=e/48, a_=e%48;           // [iy*48+ix] <- input [ix*48+iy]
        float nv = n_pred[a_*48+i_];
        nk[e] = (float)(k2*(double)nv*(double)nv);
        bb[e] = xb[a_*48+i_];
    }
    __syncthreads();

    const int dir    = (wid==0) ? 1 : -1;
    const int ibeg   = (wid==0) ? 0 : 47;
    const int nsteps = (wid==0) ? 25 : 23;   // wave0 step 24 = partial (S_24 only)

    v2 g[6][6];
    v2 m[6][6];
    v2 zrow[6];
    #pragma unroll
    for (int i=0;i<6;++i) zrow[i] = mk2(0.f,0.f);

    // ================= two-sided forward elimination =================
    #pragma unroll 1
    for (int step=0; step<nsteps; ++step){
        int ib = ibeg + dir*step;
        bool full = !(wid==0 && step==24);

        v2 zc[6];
        #pragma unroll
        for (int j=0;j<6;++j) zc[j] = shfl_c(zrow[j], diagl);

        v2 nci = mk2(0.f,0.f), czp = mk2(0.f,0.f);
        if (step>0){
            if (dir>0){ nci = cmul(lov[ib], hiv[ib-1]); czp = lov[ib]; }
            else      { nci = cmul(hiv[ib], lov[ib+1]); czp = hiv[ib]; }
            nci = -nci;
        }
        bool same  = (lc==lr), rightn = (lc==lr+1), leftn = (lc+1==lr);
        v2 p[6];
        #pragma unroll
        for (int i=0;i<6;++i){
            int r = r0+i;
            v2 dgr = dgv[r], lor = lov[r], hir = hiv[r];
            v2 ddi = dgv[ib] + dgr + mk2(nk[ib*48+r],0.f);
            v2 acc = mk2(0.f,0.f);
            #pragma unroll
            for (int j=0;j<6;++j){
                v2 v = (step>0)? cmul(nci, g[i][j]) : mk2(0.f,0.f);
                if (same){
                    if (j==i)   v = v + ddi;
                    if (j==i+1) v = v + hir;
                    if (j+1==i) v = v + lor;
                }
                if (rightn && i==5 && j==0) v = v + hir;
                if (leftn  && i==0 && j==5) v = v + lor;
                m[i][j] = v;
                if (step>0) acc = cfma_(acc, g[i][j], zc[j]);
            }
            p[i] = acc;
        }
        if (step>0){
            #pragma unroll
            for (int i=0;i<6;++i){
                v2 w = bfly_c(p[i]);
                zrow[i] = cfms(mk2(bb[ib*48+r0+i],0.f), czp, w);
            }
        } else {
            #pragma unroll
            for (int i=0;i<6;++i) zrow[i] = mk2(bb[ib*48+r0+i], 0.f);
        }
        if (lc==0){
            #pragma unroll
            for (int i=0;i<6;++i) zv[ib*48+r0+i] = zrow[i];
        }

        if (full){
            gj48(m, lr, lc);
            if (ib == 25){
                #pragma unroll
                for (int i=0;i<6;++i)
                    #pragma unroll
                    for (int j=0;j<6;++j) Hx[(r0+i)*48 + c0v + j] = m[i][j];
            } else {
                #pragma unroll
                for (int i=0;i<6;++i){
                    float4* w4 = (float4*)(wsG + 2*((size_t)ib*NN + (r0+i)*48 + c0v));
                    #pragma unroll
                    for (int jp=0;jp<3;++jp){
                        float4 f;
                        f.x = m[i][2*jp].x;   f.y = m[i][2*jp].y;
                        f.z = m[i][2*jp+1].x; f.w = m[i][2*jp+1].y;
                        w4[jp] = f;
                    }
                }
            }
            #pragma unroll
            for (int i=0;i<6;++i)
                #pragma unroll
                for (int j=0;j<6;++j) g[i][j] = m[i][j];
        }
    }

    // wave 1: v = H_25 * w_25 into LDS
    if (wid==1){
        v2 zc[6];
        #pragma unroll
        for (int j=0;j<6;++j) zc[j] = shfl_c(zrow[j], diagl);
        #pragma unroll
        for (int i=0;i<6;++i){
            v2 acc = mk2(0.f,0.f);
            #pragma unroll
            for (int j=0;j<6;++j) acc = cfma_(acc, m[i][j], zc[j]);
            acc = bfly_c(acc);
            if (lc==0) vv[r0+i] = acc;
        }
    }
    __syncthreads();

    // ================= interface (wave 0) =================
    v2 xrow[6];
    if (wid==0){
        // m = S_24, zrow = z_24 (valid all lanes)
        v2 cf = cmul(hiv[24], lov[25]);
        #pragma unroll
        for (int i=0;i<6;++i)
            #pragma unroll
            for (int j=0;j<6;++j) m[i][j] = cfms(m[i][j], cf, Hx[(r0+i)*48 + c0v + j]);
        #pragma unroll
        for (int i=0;i<6;++i) zrow[i] = cfms(zrow[i], hiv[24], vv[r0+i]);
        gj48(m, lr, lc);    // m = F^{-1}
        v2 zc[6];
        #pragma unroll
        for (int j=0;j<6;++j) zc[j] = shfl_c(zrow[j], diagl);
        #pragma unroll
        for (int i=0;i<6;++i){
            v2 acc = mk2(0.f,0.f);
            #pragma unroll
            for (int j=0;j<6;++j) acc = cfma_(acc, m[i][j], zc[j]);
            xrow[i] = bfly_c(acc);
        }
        if (lc==0){
            #pragma unroll
            for (int i=0;i<6;++i) zv[24*48+r0+i] = xrow[i];
        }
        // x_25 = H_25 (w_25 - lov[25] x_24)
        v2 xc[6], tm[6];
        #pragma unroll
        for (int j=0;j<6;++j) xc[j] = shfl_c(xrow[j], diagl);
        #pragma unroll
        for (int j=0;j<6;++j) tm[j] = cfms(zv[25*48+c0v+j], lov[25], xc[j]);
        #pragma unroll
        for (int i=0;i<6;++i){
            v2 acc = mk2(0.f,0.f);
            #pragma unroll
            for (int j=0;j<6;++j) acc = cfma_(acc, Hx[(r0+i)*48 + c0v + j], tm[j]);
            acc = bfly_c(acc);
            if (lc==0) zv[25*48+r0+i] = acc;
        }
    }
    __syncthreads();

    // ================= parallel back-substitution =================
    if (wid==0){
        #pragma unroll 1
        for (int ib=23; ib>=0; --ib){
            v2 xc[6], tm[6];
            #pragma unroll
            for (int j=0;j<6;++j) xc[j] = shfl_c(xrow[j], diagl);
            v2 hiib = hiv[ib];
            #pragma unroll
            for (int j=0;j<6;++j) tm[j] = cfms(zv[ib*48+c0v+j], hiib, xc[j]);
            #pragma unroll
            for (int i=0;i<6;++i){
                const float4* w4 = (const float4*)(wsG + 2*((size_t)ib*NN + (r0+i)*48 + c0v));
                v2 acc = mk2(0.f,0.f);
                #pragma unroll
                for (int jp=0;jp<3;++jp){
                    float4 f = w4[jp];
                    acc = cfma_(acc, mk2(f.x,f.y), tm[2*jp]);
                    acc = cfma_(acc, mk2(f.z,f.w), tm[2*jp+1]);
                }
                xrow[i] = bfly_c(acc);
            }
            if (lc==0){
                #pragma unroll
                for (int i=0;i<6;++i) zv[ib*48+r0+i] = xrow[i];
            }
        }
    } else {
        #pragma unroll
        for (int i=0;i<6;++i) xrow[i] = zv[25*48+r0+i];
        #pragma unroll 1
        for (int ib=26; ib<NXY; ++ib){
            v2 xc[6], tm[6];
            #pragma unroll
            for (int j=0;j<6;++j) xc[j] = shfl_c(xrow[j], diagl);
            v2 loib = lov[ib];
            #pragma unroll
            for (int j=0;j<6;++j) tm[j] = cfms(zv[ib*48+c0v+j], loib, xc[j]);
            #pragma unroll
            for (int i=0;i<6;++i){
                const float4* w4 = (const float4*)(wsG + 2*((size_t)ib*NN + (r0+i)*48 + c0v));
                v2 acc = mk2(0.f,0.f);
                #pragma unroll
                for (int jp=0;jp<3;++jp){
                    float4 f = w4[jp];
                    acc = cfma_(acc, mk2(f.x,f.y), tm[2*jp]);
                    acc = cfma_(acc, mk2(f.z,f.w), tm[2*jp+1]);
                }
                xrow[i] = bfly_c(acc);
            }
            if (lc==0){
                #pragma unroll
                for (int i=0;i<6;++i) zv[ib*48+r0+i] = xrow[i];
            }
        }
    }
    __syncthreads();

    // ================= epilogue =================
    for (int e=t; e<NN; e+=128){
        int alpha=e/48, beta=e%48;
        v2 psi = zv[beta*48+alpha];
        float y0=yaim[2*e], y1=yaim[2*e+1];
        if (out_size == NN*4){
            float4 o = make_float4(psi.x*y0, psi.x*y1, y0*y0, y1*y1);
            *(float4*)(out + 4*e) = o;
        } else {
            float* o = out + 8*e;
            o[0]=psi.x*y0; o[1]=psi.y*y0; o[2]=psi.x*y1; o[3]=psi.y*y1;
            o[4]=y0*y0; o[5]=0.f; o[6]=y1*y1; o[7]=0.f;
        }
    }
}

extern "C" void kernel_launch(void* const* d_in, const int* in_sizes, int n_in,
                              void* d_out, int out_size, void* d_ws, size_t ws_size,
                              hipStream_t stream) {
    const float* n_pred = (const float*)d_in[0];   // n_prediction
    const float* xb     = (const float*)d_in[2];   // x_b
    const float* ya     = (const float*)d_in[3];   // y_aim
    float* out = (float*)d_out;
    float* wsG = (float*)d_ws;                     // 48*2304*8 = 884736 B

    hipLaunchKernelGGL(helm_babe, dim3(1), dim3(128), 0, stream,
                       n_pred, xb, ya, out, out_size, wsG);
}